// Round 4
// baseline (2705.534 us; speedup 1.0000x reference)
//
#include <hip/hip_runtime.h>
#include <hip/hip_bf16.h>

#define T_STEPS 128
#define L2E  1.44269504f   // log2(e)
#define L2E2 2.88539008f   // 2*log2(e)

typedef __attribute__((ext_vector_type(8))) short short8;
typedef __attribute__((ext_vector_type(4))) float f32x4;

// One wave = one 16-batch tile. Per step:
//   gates[16b x 128gu] = hprev[16 x 32] @ W_hh.T + x_t*W_ih.T + b   (MFMA)
// then the LSTM cell evaluated with 5 exp2 + 2 rcp per (batch,unit) pair:
//   all weights pre-scaled by log2e (2*log2e for g-gate), so gate values are
//   already exp2 arguments.
//   c' = [ef*c*(ei+1)(eg+1) + ei*(eg-1)(ef+1)] / [(ef+1)(ei+1)(eg+1)]
//   h  = eo*(ec-1) / [(eo+1)(ec+1)],  ec = exp2(2*log2e*c')
// h is carried hi/lo-split in bf16 (2 MFMAs per gate block) to keep the
// recurrence quantization ~1e-5.
extern "C" __global__ void __launch_bounds__(256, 4)
lstm_mfma_kernel(const float* __restrict__ x,
                 const float* __restrict__ W_ih,
                 const float* __restrict__ W_hh,
                 const float* __restrict__ b_ih,
                 const float* __restrict__ b_hh,
                 const float* __restrict__ W_fc,
                 const float* __restrict__ b_fc,
                 float* __restrict__ out, int B)
{
    __shared__ unsigned int hhi[4][256];       // h_hi [16 rows][16 u32] bf16x2
    __shared__ unsigned int hlo[4][256];       // h_lo

    const int widx = threadIdx.x >> 6;
    const int lane = threadIdx.x & 63;
    const int p    = lane & 15;      // tile column (batch for A-read, unit-pair for D)
    const int g4   = lane >> 4;      // quarter-wave 0..3
    const int btile = (blockIdx.x * 4 + widx) * 16;
    if (btile >= B) return;

    unsigned int* hh = &hhi[widx][0];
    unsigned int* hl = &hlo[widx][0];

    // zero h tiles (h0 = 0)
    #pragma unroll
    for (int q = 0; q < 4; ++q) { hh[q * 64 + lane] = 0u; hl[q * 64 + lane] = 0u; }

    // ---- per-lane constants: W_hh B-fragments (scaled, bf16 RTN), bias, W_ih
    short8 wfrag[8];
    float  biasv[8], wihv[8];
    #pragma unroll
    for (int m = 0; m < 8; ++m) {
        int gu = (m >> 1) * 32 + 2 * p + (m & 1);
        float scale = (m >> 1) == 2 ? L2E2 : L2E;   // g-gate feeds exp2(2g*log2e)
        biasv[m] = (b_ih[gu] + b_hh[gu]) * scale;
        wihv[m]  = W_ih[gu] * scale;
        const float* wr = W_hh + gu * 32 + g4 * 8;   // 8 consecutive k
        short8 w;
        #pragma unroll
        for (int e = 0; e < 8; ++e) {
            unsigned int bits = __float_as_uint(wr[e] * scale);
            bits = bits + 0x7FFFu + ((bits >> 16) & 1u);   // RTN to bf16
            w[e] = (short)(bits >> 16);
        }
        wfrag[m] = w;
    }

    __builtin_amdgcn_wave_barrier();   // LDS zero-writes ordered before loop reads

    const float* xrow = x + (size_t)(btile + g4 * 4) * T_STEPS;

    float cst[2][4];   // c state: [unit-half u][batch-reg r]
    float hn[2][4];
    #pragma unroll
    for (int u = 0; u < 2; ++u)
        #pragma unroll
        for (int r = 0; r < 4; ++r) cst[u][r] = 0.0f;

    for (int tb = 0; tb < T_STEPS; tb += 4) {
        // 4 steps of x for my 4 batch rows, straight from global (L1-resident:
        // 16 lanes per quarter-group read the same rows)
        f32x4 xq[4];
        #pragma unroll
        for (int r = 0; r < 4; ++r)
            xq[r] = *reinterpret_cast<const f32x4*>(xrow + r * T_STEPS + tb);

        #pragma unroll
        for (int s = 0; s < 4; ++s) {
            // acc init = scaled bias + x*scaled W_ih  (f32, exact)
            f32x4 acc[8];
            #pragma unroll
            for (int m = 0; m < 8; ++m) {
                f32x4 a;
                #pragma unroll
                for (int r = 0; r < 4; ++r) a[r] = fmaf(xq[r][s], wihv[m], biasv[m]);
                acc[m] = a;
            }

            // previous h as A-fragments: row=lane&15 (batch), k=g4*8+e
            short8 ahi = *reinterpret_cast<short8*>(&hh[p * 16 + g4 * 4]);
            short8 alo = *reinterpret_cast<short8*>(&hl[p * 16 + g4 * 4]);

            #pragma unroll
            for (int m = 0; m < 8; ++m) {
                acc[m] = __builtin_amdgcn_mfma_f32_16x16x32_bf16(ahi, wfrag[m], acc[m], 0, 0, 0);
                acc[m] = __builtin_amdgcn_mfma_f32_16x16x32_bf16(alo, wfrag[m], acc[m], 0, 0, 0);
            }

            // LSTM cell: 5 exp2 + 2 rcp per (batch,unit) pair, lane-local
            #pragma unroll
            for (int u = 0; u < 2; ++u) {
                #pragma unroll
                for (int r = 0; r < 4; ++r) {
                    float ei = __builtin_amdgcn_exp2f(acc[0 + u][r]);
                    float ef = __builtin_amdgcn_exp2f(acc[2 + u][r]);
                    float eg = __builtin_amdgcn_exp2f(acc[4 + u][r]);
                    float eo = __builtin_amdgcn_exp2f(acc[6 + u][r]);
                    float ef1 = ef + 1.0f, ei1 = ei + 1.0f, eg1 = eg + 1.0f;
                    float P   = ei1 * eg1;
                    float num = fmaf(ef * cst[u][r], P, ei * (eg - 1.0f) * ef1);
                    float cn  = num * __builtin_amdgcn_rcpf(P * ef1);
                    cst[u][r] = cn;
                    float ec  = __builtin_amdgcn_exp2f(cn * L2E2);
                    hn[u][r]  = eo * (ec - 1.0f)
                              * __builtin_amdgcn_rcpf((eo + 1.0f) * (ec + 1.0f));
                }
            }

            // pack h -> bf16 hi (truncate) + lo (residual), write to LDS
            #pragma unroll
            for (int r = 0; r < 4; ++r) {
                unsigned int x0 = __float_as_uint(hn[0][r]);
                unsigned int x1 = __float_as_uint(hn[1][r]);
                unsigned int hiw = (x0 >> 16) | (x1 & 0xFFFF0000u);
                float res0 = hn[0][r] - __uint_as_float(x0 & 0xFFFF0000u);
                float res1 = hn[1][r] - __uint_as_float(x1 & 0xFFFF0000u);
                unsigned int low = (__float_as_uint(res0) >> 16)
                                 | (__float_as_uint(res1) & 0xFFFF0000u);
                int rb = g4 * 4 + r;
                hh[rb * 16 + p] = hiw;
                hl[rb * 16 + p] = low;
            }
            __builtin_amdgcn_wave_barrier();   // order writes before next iter's reads
        }
    }

    // ---- FC head: out[b][o] = sum_j h[b][j]*W_fc[o][j] + b_fc[o]
    float wfc00 = W_fc[2 * p], wfc01 = W_fc[2 * p + 1];
    float wfc10 = W_fc[32 + 2 * p], wfc11 = W_fc[32 + 2 * p + 1];
    float bfc0 = b_fc[0], bfc1 = b_fc[1];
    #pragma unroll
    for (int r = 0; r < 4; ++r) {
        float o0 = fmaf(hn[0][r], wfc00, hn[1][r] * wfc01);
        float o1 = fmaf(hn[0][r], wfc10, hn[1][r] * wfc11);
        #pragma unroll
        for (int m = 8; m >= 1; m >>= 1) {   // reduce across p (16-lane group)
            o0 += __shfl_xor(o0, m, 64);
            o1 += __shfl_xor(o1, m, 64);
        }
        if (p == 0) {
            size_t b = (size_t)(btile + g4 * 4 + r);
            out[b * 2 + 0] = o0 + bfc0;
            out[b * 2 + 1] = o1 + bfc1;
        }
    }
}

extern "C" void kernel_launch(void* const* d_in, const int* in_sizes, int n_in,
                              void* d_out, int out_size, void* d_ws, size_t ws_size,
                              hipStream_t stream) {
    const float* x    = (const float*)d_in[0];
    const float* W_ih = (const float*)d_in[1];
    const float* W_hh = (const float*)d_in[2];
    const float* b_ih = (const float*)d_in[3];
    const float* b_hh = (const float*)d_in[4];
    const float* W_fc = (const float*)d_in[5];
    const float* b_fc = (const float*)d_in[6];
    float* out = (float*)d_out;

    int B = in_sizes[0] / T_STEPS;
    int grid = (B + 63) / 64;   // 64 batch per block (4 waves x 16)
    hipLaunchKernelGGL(lstm_mfma_kernel, dim3(grid), dim3(256), 0, stream,
                       x, W_ih, W_hh, b_ih, b_hh, W_fc, b_fc, out, B);
}

// Round 6
// 747.500 us; speedup vs baseline: 3.6194x; 3.6194x over previous
//
#include <hip/hip_runtime.h>
#include <hip/hip_bf16.h>

#define T_STEPS 128
#define L2E  1.44269504f   // log2(e)
#define L2E2 2.88539008f   // 2*log2(e)

typedef __attribute__((ext_vector_type(8))) short short8;
typedef __attribute__((ext_vector_type(4))) float f32x4;

// One wave = one 16-batch tile. Per step:
//   gates[16b x 128gu] = hprev[16 x 32] @ W_hh.T + x_t*W_ih.T + b   (MFMA)
// then the LSTM cell evaluated with 5 exp2 + 2 rcp per (batch,unit) pair:
//   all weights pre-scaled by log2e (2*log2e for g-gate), so gate values are
//   already exp2 arguments.
//   c' = [ef*c*(ei+1)(eg+1) + ei*(eg-1)(ef+1)] / [(ef+1)(ei+1)(eg+1)]
//   h  = eo*(ec-1) / [(eo+1)(ec+1)],  ec = exp2(2*log2e*c')
// h is carried hi/lo-split in bf16 (2 MFMAs per gate block) to keep the
// recurrence quantization ~1e-5.
//
// NOTE: plain __launch_bounds__(256). Round 4's (256,4) halved the unified
// VGPR/AGPR budget to 128 -> massive scratch spill (WRITE_SIZE 888 MB,
// FETCH 9.3 GB, 3.3x slowdown). Do not re-add a min-waves hint here.
extern "C" __global__ void __launch_bounds__(256)
lstm_mfma_kernel(const float* __restrict__ x,
                 const float* __restrict__ W_ih,
                 const float* __restrict__ W_hh,
                 const float* __restrict__ b_ih,
                 const float* __restrict__ b_hh,
                 const float* __restrict__ W_fc,
                 const float* __restrict__ b_fc,
                 float* __restrict__ out, int B)
{
    __shared__ unsigned int hhi[4][256];       // h_hi [16 rows][16 u32] bf16x2
    __shared__ unsigned int hlo[4][256];       // h_lo

    const int widx = threadIdx.x >> 6;
    const int lane = threadIdx.x & 63;
    const int p    = lane & 15;      // tile column (batch for A-read, unit-pair for D)
    const int g4   = lane >> 4;      // quarter-wave 0..3
    const int btile = (blockIdx.x * 4 + widx) * 16;
    if (btile >= B) return;

    unsigned int* hh = &hhi[widx][0];
    unsigned int* hl = &hlo[widx][0];

    // zero h tiles (h0 = 0)
    #pragma unroll
    for (int q = 0; q < 4; ++q) { hh[q * 64 + lane] = 0u; hl[q * 64 + lane] = 0u; }

    // ---- per-lane constants: W_hh B-fragments (scaled, bf16 RTN), bias, W_ih
    short8 wfrag[8];
    float  biasv[8], wihv[8];
    #pragma unroll
    for (int m = 0; m < 8; ++m) {
        int gu = (m >> 1) * 32 + 2 * p + (m & 1);
        float scale = (m >> 1) == 2 ? L2E2 : L2E;   // g-gate feeds exp2(2g*log2e)
        biasv[m] = (b_ih[gu] + b_hh[gu]) * scale;
        wihv[m]  = W_ih[gu] * scale;
        const float* wr = W_hh + gu * 32 + g4 * 8;   // 8 consecutive k
        short8 w;
        #pragma unroll
        for (int e = 0; e < 8; ++e) {
            unsigned int bits = __float_as_uint(wr[e] * scale);
            bits = bits + 0x7FFFu + ((bits >> 16) & 1u);   // RTN to bf16
            w[e] = (short)(bits >> 16);
        }
        wfrag[m] = w;
    }

    __builtin_amdgcn_wave_barrier();   // LDS zero-writes ordered before loop reads

    const float* xrow = x + (size_t)(btile + g4 * 4) * T_STEPS;

    float cst[2][4];   // c state: [unit-half u][batch-reg r]
    float hn[2][4];
    #pragma unroll
    for (int u = 0; u < 2; ++u)
        #pragma unroll
        for (int r = 0; r < 4; ++r) cst[u][r] = 0.0f;

    for (int tb = 0; tb < T_STEPS; tb += 4) {
        // 4 steps of x for my 4 batch rows (16-lane broadcast reads, ~270 MB
        // worst-case HBM traffic -- negligible)
        f32x4 xq[4];
        #pragma unroll
        for (int r = 0; r < 4; ++r)
            xq[r] = *reinterpret_cast<const f32x4*>(xrow + r * T_STEPS + tb);

        #pragma unroll
        for (int s = 0; s < 4; ++s) {
            // acc init = scaled bias + x*scaled W_ih  (f32, exact)
            f32x4 acc[8];
            #pragma unroll
            for (int m = 0; m < 8; ++m) {
                f32x4 a;
                #pragma unroll
                for (int r = 0; r < 4; ++r) a[r] = fmaf(xq[r][s], wihv[m], biasv[m]);
                acc[m] = a;
            }

            // previous h as A-fragments: row=lane&15 (batch), k=g4*8+e
            short8 ahi = *reinterpret_cast<short8*>(&hh[p * 16 + g4 * 4]);
            short8 alo = *reinterpret_cast<short8*>(&hl[p * 16 + g4 * 4]);

            #pragma unroll
            for (int m = 0; m < 8; ++m) {
                acc[m] = __builtin_amdgcn_mfma_f32_16x16x32_bf16(ahi, wfrag[m], acc[m], 0, 0, 0);
                acc[m] = __builtin_amdgcn_mfma_f32_16x16x32_bf16(alo, wfrag[m], acc[m], 0, 0, 0);
            }

            // LSTM cell: 5 exp2 + 2 rcp per (batch,unit) pair, lane-local
            #pragma unroll
            for (int u = 0; u < 2; ++u) {
                #pragma unroll
                for (int r = 0; r < 4; ++r) {
                    float ei = __builtin_amdgcn_exp2f(acc[0 + u][r]);
                    float ef = __builtin_amdgcn_exp2f(acc[2 + u][r]);
                    float eg = __builtin_amdgcn_exp2f(acc[4 + u][r]);
                    float eo = __builtin_amdgcn_exp2f(acc[6 + u][r]);
                    float ef1 = ef + 1.0f, ei1 = ei + 1.0f, eg1 = eg + 1.0f;
                    float P   = ei1 * eg1;
                    float num = fmaf(ef * cst[u][r], P, ei * (eg - 1.0f) * ef1);
                    float cn  = num * __builtin_amdgcn_rcpf(P * ef1);
                    cst[u][r] = cn;
                    float ec  = __builtin_amdgcn_exp2f(cn * L2E2);
                    hn[u][r]  = eo * (ec - 1.0f)
                              * __builtin_amdgcn_rcpf((eo + 1.0f) * (ec + 1.0f));
                }
            }

            // pack h -> bf16 hi (truncate) + lo (residual), write to LDS
            #pragma unroll
            for (int r = 0; r < 4; ++r) {
                unsigned int x0 = __float_as_uint(hn[0][r]);
                unsigned int x1 = __float_as_uint(hn[1][r]);
                unsigned int hiw = (x0 >> 16) | (x1 & 0xFFFF0000u);
                float res0 = hn[0][r] - __uint_as_float(x0 & 0xFFFF0000u);
                float res1 = hn[1][r] - __uint_as_float(x1 & 0xFFFF0000u);
                unsigned int low = (__float_as_uint(res0) >> 16)
                                 | (__float_as_uint(res1) & 0xFFFF0000u);
                int rb = g4 * 4 + r;
                hh[rb * 16 + p] = hiw;
                hl[rb * 16 + p] = low;
            }
            __builtin_amdgcn_wave_barrier();   // order writes before next iter's reads
        }
    }

    // ---- FC head: out[b][o] = sum_j h[b][j]*W_fc[o][j] + b_fc[o]
    float wfc00 = W_fc[2 * p], wfc01 = W_fc[2 * p + 1];
    float wfc10 = W_fc[32 + 2 * p], wfc11 = W_fc[32 + 2 * p + 1];
    float bfc0 = b_fc[0], bfc1 = b_fc[1];
    #pragma unroll
    for (int r = 0; r < 4; ++r) {
        float o0 = fmaf(hn[0][r], wfc00, hn[1][r] * wfc01);
        float o1 = fmaf(hn[0][r], wfc10, hn[1][r] * wfc11);
        #pragma unroll
        for (int m = 8; m >= 1; m >>= 1) {   // reduce across p (16-lane group)
            o0 += __shfl_xor(o0, m, 64);
            o1 += __shfl_xor(o1, m, 64);
        }
        if (p == 0) {
            size_t b = (size_t)(btile + g4 * 4 + r);
            out[b * 2 + 0] = o0 + bfc0;
            out[b * 2 + 1] = o1 + bfc1;
        }
    }
}

extern "C" void kernel_launch(void* const* d_in, const int* in_sizes, int n_in,
                              void* d_out, int out_size, void* d_ws, size_t ws_size,
                              hipStream_t stream) {
    const float* x    = (const float*)d_in[0];
    const float* W_ih = (const float*)d_in[1];
    const float* W_hh = (const float*)d_in[2];
    const float* b_ih = (const float*)d_in[3];
    const float* b_hh = (const float*)d_in[4];
    const float* W_fc = (const float*)d_in[5];
    const float* b_fc = (const float*)d_in[6];
    float* out = (float*)d_out;

    int B = in_sizes[0] / T_STEPS;
    int grid = (B + 63) / 64;   // 64 batch per block (4 waves x 16)
    hipLaunchKernelGGL(lstm_mfma_kernel, dim3(grid), dim3(256), 0, stream,
                       x, W_ih, W_hh, b_ih, b_hh, W_fc, b_fc, out, B);
}

// Round 8
// 719.922 us; speedup vs baseline: 3.7581x; 1.0383x over previous
//
#include <hip/hip_runtime.h>
#include <hip/hip_bf16.h>

#define T_STEPS 128
#define L2E  1.44269504f   // log2(e)
#define L2E2 2.88539008f   // 2*log2(e)

typedef __attribute__((ext_vector_type(8))) short short8;
typedef __attribute__((ext_vector_type(4))) float f32x4;
typedef __attribute__((ext_vector_type(2))) float f32x2;

// One wave = one 16-batch tile. Per step:
//   gates[16b x 128gu] = hprev[16 x 32] @ W_hh.T + x_t*W_ih.T + b   (MFMA)
// Cell algebra (weights pre-scaled by log2e; 2*log2e for g-gate):
//   c' = [ef*c*(ei+1)(eg+1) + ei*(eg-1)(ef+1)] / [(ef+1)(ei+1)(eg+1)]
//   h  = eo*(ec-1) / [(eo+1)(ec+1)],  ec = exp2(2*log2e*c')
// -> 4 exp2 + 1 tanh-exp2 per pair; reciprocals PAIRED across the two
// components of each f32x2 group (1/a = b*rcp(ab)) -> 8 rcp/step not 16.
// Cell math on f32x2 ext-vectors so the compiler can emit v_pk_*_f32
// (the two components are adjacent accumulator regs -> zero-move packing).
// h carried hi/lo-split bf16 (2 MFMAs per gate block): recurrence quant ~1e-5.
//
// NOTE: plain __launch_bounds__(256). (256,4) halves the unified VGPR/AGPR
// budget to 128 -> catastrophic scratch spill (round 4: 9.3 GB FETCH).
extern "C" __global__ void __launch_bounds__(256)
lstm_mfma_kernel(const float* __restrict__ x,
                 const float* __restrict__ W_ih,
                 const float* __restrict__ W_hh,
                 const float* __restrict__ b_ih,
                 const float* __restrict__ b_hh,
                 const float* __restrict__ W_fc,
                 const float* __restrict__ b_fc,
                 float* __restrict__ out, int B)
{
    __shared__ unsigned int hhi[4][256];       // h_hi [16 rows][16 u32] bf16x2
    __shared__ unsigned int hlo[4][256];       // h_lo

    const int widx = threadIdx.x >> 6;
    const int lane = threadIdx.x & 63;
    const int p    = lane & 15;      // tile column
    const int g4   = lane >> 4;      // quarter-wave 0..3
    const int btile = (blockIdx.x * 4 + widx) * 16;
    if (btile >= B) return;

    unsigned int* hh = &hhi[widx][0];
    unsigned int* hl = &hlo[widx][0];

    // zero h tiles (h0 = 0)
    #pragma unroll
    for (int q = 0; q < 4; ++q) { hh[q * 64 + lane] = 0u; hl[q * 64 + lane] = 0u; }

    // ---- per-lane constants: W_hh B-fragments (scaled, bf16 RTN), bias, W_ih
    short8 wfrag[8];
    float  biasv[8], wihv[8];
    #pragma unroll
    for (int m = 0; m < 8; ++m) {
        int gu = (m >> 1) * 32 + 2 * p + (m & 1);
        float scale = (m >> 1) == 2 ? L2E2 : L2E;   // g-gate feeds exp2(2g*log2e)
        biasv[m] = (b_ih[gu] + b_hh[gu]) * scale;
        wihv[m]  = W_ih[gu] * scale;
        const float* wr = W_hh + gu * 32 + g4 * 8;   // 8 consecutive k
        short8 w;
        #pragma unroll
        for (int e = 0; e < 8; ++e) {
            unsigned int bits = __float_as_uint(wr[e] * scale);
            bits = bits + 0x7FFFu + ((bits >> 16) & 1u);   // RTN to bf16
            w[e] = (short)(bits >> 16);
        }
        wfrag[m] = w;
    }

    __builtin_amdgcn_wave_barrier();   // LDS zero-writes ordered before loop reads

    const float* xrow = x + (size_t)(btile + g4 * 4) * T_STEPS;

    // state: [u][rp] f32x2 over batch-reg pairs (r = 2*rp + component)
    f32x2 cst2[2][2];
    f32x2 hn2[2][2];
    cst2[0][0] = 0.0f; cst2[0][1] = 0.0f; cst2[1][0] = 0.0f; cst2[1][1] = 0.0f;

    const f32x2 one2 = 1.0f;

    for (int tb = 0; tb < T_STEPS; tb += 4) {
        f32x4 xq[4];
        #pragma unroll
        for (int r = 0; r < 4; ++r)
            xq[r] = *reinterpret_cast<const f32x4*>(xrow + r * T_STEPS + tb);

        #pragma unroll
        for (int s = 0; s < 4; ++s) {
            // acc init = scaled bias + x*scaled W_ih  (f32, exact)
            f32x4 acc[8];
            #pragma unroll
            for (int m = 0; m < 8; ++m) {
                f32x4 a;
                #pragma unroll
                for (int r = 0; r < 4; ++r) a[r] = fmaf(xq[r][s], wihv[m], biasv[m]);
                acc[m] = a;
            }

            // previous h as A-fragments: row=lane&15 (batch), k=g4*8+e
            short8 ahi = *reinterpret_cast<short8*>(&hh[p * 16 + g4 * 4]);
            short8 alo = *reinterpret_cast<short8*>(&hl[p * 16 + g4 * 4]);

            #pragma unroll
            for (int m = 0; m < 8; ++m) {
                acc[m] = __builtin_amdgcn_mfma_f32_16x16x32_bf16(ahi, wfrag[m], acc[m], 0, 0, 0);
                acc[m] = __builtin_amdgcn_mfma_f32_16x16x32_bf16(alo, wfrag[m], acc[m], 0, 0, 0);
            }

            // ---- LSTM cell on f32x2 groups (2 batch rows per group).
            // EXT picks the low (r=0,1) or high (r=2,3) half of the f32x4 acc.
            #define GETLO(v) __builtin_shufflevector((v), (v), 0, 1)
            #define GETHI(v) __builtin_shufflevector((v), (v), 2, 3)
            #define CELL(U, RP, EXT) {                                          \
                f32x2 gi2 = EXT(acc[0 + (U)]);                                  \
                f32x2 gf2 = EXT(acc[2 + (U)]);                                  \
                f32x2 gg2 = EXT(acc[4 + (U)]);                                  \
                f32x2 go2 = EXT(acc[6 + (U)]);                                  \
                f32x2 ei2, ef2, eg2, eo2;                                       \
                ei2[0] = __builtin_amdgcn_exp2f(gi2[0]);                        \
                ei2[1] = __builtin_amdgcn_exp2f(gi2[1]);                        \
                ef2[0] = __builtin_amdgcn_exp2f(gf2[0]);                        \
                ef2[1] = __builtin_amdgcn_exp2f(gf2[1]);                        \
                eg2[0] = __builtin_amdgcn_exp2f(gg2[0]);                        \
                eg2[1] = __builtin_amdgcn_exp2f(gg2[1]);                        \
                eo2[0] = __builtin_amdgcn_exp2f(go2[0]);                        \
                eo2[1] = __builtin_amdgcn_exp2f(go2[1]);                        \
                f32x2 ef1 = ef2 + one2, ei1 = ei2 + one2, eg1 = eg2 + one2;     \
                f32x2 P    = ei1 * eg1;                                         \
                f32x2 denc = P * ef1;                                           \
                f32x2 t2   = (ei2 * (eg2 - one2)) * ef1;                        \
                f32x2 num  = (ef2 * cst2[U][RP]) * P + t2;                      \
                /* paired rcp across the 2 components */                        \
                float pc  = denc[0] * denc[1];                                  \
                float rc  = __builtin_amdgcn_rcpf(pc);                          \
                f32x2 rc2; rc2[0] = denc[1] * rc; rc2[1] = denc[0] * rc;        \
                f32x2 cn2 = num * rc2;                                          \
                cst2[U][RP] = cn2;                                              \
                f32x2 ec2;                                                      \
                ec2[0] = __builtin_amdgcn_exp2f(cn2[0] * L2E2);                 \
                ec2[1] = __builtin_amdgcn_exp2f(cn2[1] * L2E2);                 \
                f32x2 eo1 = eo2 + one2, ec1 = ec2 + one2;                       \
                f32x2 denh = eo1 * ec1;                                         \
                f32x2 numh = eo2 * (ec2 - one2);                                \
                float ph  = denh[0] * denh[1];                                  \
                float rh  = __builtin_amdgcn_rcpf(ph);                          \
                f32x2 rh2; rh2[0] = denh[1] * rh; rh2[1] = denh[0] * rh;        \
                hn2[U][RP] = numh * rh2; }
            CELL(0, 0, GETLO)
            CELL(0, 1, GETHI)
            CELL(1, 0, GETLO)
            CELL(1, 1, GETHI)
            #undef CELL
            #undef GETLO
            #undef GETHI

            // pack h -> bf16 hi (truncate) + lo (residual), write to LDS
            #define PACKR(R, RP, J) {                                           \
                float h0 = hn2[0][RP][J];                                       \
                float h1 = hn2[1][RP][J];                                       \
                unsigned int x0 = __float_as_uint(h0);                          \
                unsigned int x1 = __float_as_uint(h1);                          \
                unsigned int hiw = (x0 >> 16) | (x1 & 0xFFFF0000u);             \
                float res0 = h0 - __uint_as_float(x0 & 0xFFFF0000u);            \
                float res1 = h1 - __uint_as_float(x1 & 0xFFFF0000u);            \
                unsigned int low = (__float_as_uint(res0) >> 16)                \
                                 | (__float_as_uint(res1) & 0xFFFF0000u);       \
                int rb = g4 * 4 + (R);                                          \
                hh[rb * 16 + p] = hiw;                                          \
                hl[rb * 16 + p] = low; }
            PACKR(0, 0, 0)
            PACKR(1, 0, 1)
            PACKR(2, 1, 0)
            PACKR(3, 1, 1)
            #undef PACKR
            __builtin_amdgcn_wave_barrier();   // order writes before next iter's reads
        }
    }

    // ---- FC head: out[b][o] = sum_j h[b][j]*W_fc[o][j] + b_fc[o]
    float wfc00 = W_fc[2 * p], wfc01 = W_fc[2 * p + 1];
    float wfc10 = W_fc[32 + 2 * p], wfc11 = W_fc[32 + 2 * p + 1];
    float bfc0 = b_fc[0], bfc1 = b_fc[1];
    #define FCR(R, RP, J) {                                                     \
        float h0 = hn2[0][RP][J];                                               \
        float h1 = hn2[1][RP][J];                                               \
        float o0 = fmaf(h0, wfc00, h1 * wfc01);                                 \
        float o1 = fmaf(h0, wfc10, h1 * wfc11);                                 \
        _Pragma("unroll")                                                       \
        for (int mm = 8; mm >= 1; mm >>= 1) {                                   \
            o0 += __shfl_xor(o0, mm, 64);                                       \
            o1 += __shfl_xor(o1, mm, 64);                                       \
        }                                                                       \
        if (p == 0) {                                                           \
            size_t b = (size_t)(btile + g4 * 4 + (R));                          \
            out[b * 2 + 0] = o0 + bfc0;                                         \
            out[b * 2 + 1] = o1 + bfc1;                                         \
        } }
    FCR(0, 0, 0)
    FCR(1, 0, 1)
    FCR(2, 1, 0)
    FCR(3, 1, 1)
    #undef FCR
}

extern "C" void kernel_launch(void* const* d_in, const int* in_sizes, int n_in,
                              void* d_out, int out_size, void* d_ws, size_t ws_size,
                              hipStream_t stream) {
    const float* x    = (const float*)d_in[0];
    const float* W_ih = (const float*)d_in[1];
    const float* W_hh = (const float*)d_in[2];
    const float* b_ih = (const float*)d_in[3];
    const float* b_hh = (const float*)d_in[4];
    const float* W_fc = (const float*)d_in[5];
    const float* b_fc = (const float*)d_in[6];
    float* out = (float*)d_out;

    int B = in_sizes[0] / T_STEPS;
    int grid = (B + 63) / 64;   // 64 batch per block (4 waves x 16)
    hipLaunchKernelGGL(lstm_mfma_kernel, dim3(grid), dim3(256), 0, stream,
                       x, W_ih, W_hh, b_ih, b_hh, W_fc, b_fc, out, B);
}